// Round 1
// 523.528 us; speedup vs baseline: 1.0494x; 1.0494x over previous
//
#include <hip/hip_runtime.h>
#include <hip/hip_bf16.h>
#include <stdint.h>

#define N_NODES 100000
#define N_EDGES 1600000
#define CH 128
#define N_REL 8
#define N_PAD 100096            // N_NODES rounded up to multiple of 128 (GEMM strip pad)
#define N_KEYS (N_NODES * N_REL)

#define SCAN_BLOCKS_K 782       // ceil(N_KEYS / 1024)
#define SCAN_BLOCKS_D 98        // ceil(N_NODES / 1024)

using frag_ab = __attribute__((ext_vector_type(8))) short;  // 8 bf16
using frag_cd = __attribute__((ext_vector_type(4))) float;  // 4 fp32

__device__ __forceinline__ short f2bs(float f) {
    union { __hip_bfloat16 h; short s; } u;
    u.h = __float2bfloat16(f);
    return u.s;
}

__device__ __forceinline__ uint32_t pack2bf(float a, float b) {
    union { __hip_bfloat16 h; unsigned short s; } ua, ub;
    ua.h = __float2bfloat16(a); ub.h = __float2bfloat16(b);
    return (uint32_t)ua.s | ((uint32_t)ub.s << 16);
}

__device__ __forceinline__ float bf_lo(uint32_t u) { return __uint_as_float(u << 16); }
__device__ __forceinline__ float bf_hi(uint32_t u) { return __uint_as_float(u & 0xffff0000u); }

// ======================= TIER 1: CSR keyed by (dst*8 + rel) =======================

__global__ void count_key_kernel(const int* __restrict__ ei, const int* __restrict__ et,
                                 int* __restrict__ cnt) {
    int e = blockIdx.x * 256 + threadIdx.x;
    if (e < N_EDGES) {
        int dst = ei[N_EDGES + e];
        int r = et[e];
        atomicAdd(&cnt[dst * N_REL + r], 1);
    }
}

// --- generic two-level scan, 1024 elements per block (256 thr x int4) ---
__global__ void scan1_kernel(const int* __restrict__ cnt, int* __restrict__ bsum, int n) {
    __shared__ int sh[256];
    const int t = threadIdx.x;
    const int base = blockIdx.x * 1024 + t * 4;
    int s = 0;
    if (base + 3 < n) {
        int4 v = *(const int4*)(cnt + base);
        s = v.x + v.y + v.z + v.w;
    } else {
        for (int i = 0; i < 4; ++i) if (base + i < n) s += cnt[base + i];
    }
    sh[t] = s;
    __syncthreads();
    for (int st = 128; st > 0; st >>= 1) {
        if (t < st) sh[t] += sh[t + st];
        __syncthreads();
    }
    if (t == 0) bsum[blockIdx.x] = sh[0];
}

__global__ void scan2_kernel(int* __restrict__ bsum, int nb) {
    __shared__ int sh[1024];
    const int t = threadIdx.x;
    int v = (t < nb) ? bsum[t] : 0;
    sh[t] = v;
    __syncthreads();
    for (int s = 1; s < 1024; s <<= 1) {
        int u = (t >= s) ? sh[t - s] : 0;
        __syncthreads();
        sh[t] += u;
        __syncthreads();
    }
    if (t < nb) bsum[t] = sh[t] - v;   // exclusive
}

// in-place: cnt[i] <- exclusive_prefix_sum(cnt)[i]
__global__ void scan3_kernel(int* __restrict__ cnt, const int* __restrict__ bsum, int n) {
    __shared__ int sh[256];
    const int t = threadIdx.x;
    const int base = blockIdx.x * 1024 + t * 4;
    int4 v = make_int4(0, 0, 0, 0);
    if (base + 3 < n) {
        v = *(const int4*)(cnt + base);
    } else {
        if (base + 0 < n) v.x = cnt[base + 0];
        if (base + 1 < n) v.y = cnt[base + 1];
        if (base + 2 < n) v.z = cnt[base + 2];
        if (base + 3 < n) v.w = cnt[base + 3];
    }
    const int s = v.x + v.y + v.z + v.w;
    sh[t] = s;
    __syncthreads();
    for (int st = 1; st < 256; st <<= 1) {      // Hillis-Steele inclusive
        int u = (t >= st) ? sh[t - st] : 0;
        __syncthreads();
        sh[t] += u;
        __syncthreads();
    }
    int run = bsum[blockIdx.x] + sh[t] - s;     // exclusive prefix for this thread
    const int o0 = run, o1 = o0 + v.x, o2 = o1 + v.y, o3 = o2 + v.z;
    if (base + 3 < n) {
        *(int4*)(cnt + base) = make_int4(o0, o1, o2, o3);
    } else {
        if (base + 0 < n) cnt[base + 0] = o0;
        if (base + 1 < n) cnt[base + 1] = o1;
        if (base + 2 < n) cnt[base + 2] = o2;
        if (base + 3 < n) cnt[base + 3] = o3;
    }
}

// scatter src into (dst,rel)-sorted slots; offs[] doubles as cursor and ends as segment-END
__global__ void permute_key_kernel(const int* __restrict__ ei, const int* __restrict__ et,
                                   int* __restrict__ offs, int* __restrict__ perm) {
    int e = blockIdx.x * 256 + threadIdx.x;
    if (e < N_EDGES) {
        int dst = ei[N_EDGES + e];
        int src = ei[e];
        int r = et[e];
        int pos = atomicAdd(&offs[dst * N_REL + r], 1);
        perm[pos] = src;
    }
}

// ======================= shared helpers =======================

// x fp32 -> bf16 (flat copy of N*128 elements)
__global__ void xconv_kernel(const float* __restrict__ x, short* __restrict__ xb) {
    int g = blockIdx.x * 256 + threadIdx.x;       // one per 8 elements
    if (g >= N_NODES * CH / 8) return;
    const float4* xp = (const float4*)x;
    float4 a = xp[(size_t)g * 2], b = xp[(size_t)g * 2 + 1];
    frag_ab f;
    f[0] = f2bs(a.x); f[1] = f2bs(a.y); f[2] = f2bs(a.z); f[3] = f2bs(a.w);
    f[4] = f2bs(b.x); f[5] = f2bs(b.y); f[6] = f2bs(b.z); f[7] = f2bs(b.w);
    *(frag_ab*)(xb + (size_t)g * 8) = f;
}

// build swizzled bf16 B: Bsw[chunk][entry][8], entry = ((ks*4+quad)*8+ct)*16+m16
__global__ void bconv_kernel(const float* __restrict__ root, const float* __restrict__ W,
                             short* __restrict__ Bsw) {
    int g = blockIdx.x * 256 + threadIdx.x;
    if (g >= 9 * 2048) return;
    int chunk = g >> 11, entry = g & 2047;
    int m16 = entry & 15, ct = (entry >> 4) & 7, quad = (entry >> 7) & 3, ks = entry >> 9;
    const float* src = (chunk == 0) ? root : W + (size_t)(chunk - 1) * CH * CH;
    int col = ct * 16 + m16, kb = ks * 32 + quad * 8;
    frag_ab f;
#pragma unroll
    for (int j = 0; j < 8; ++j) f[j] = f2bs(src[(size_t)(kb + j) * CH + col]);
    *(frag_ab*)(Bsw + (size_t)g * 8) = f;
}

// ======================= FUSED aggregate + GEMM =======================
// One block = 128 output rows. Per relation r: aggregate the 128 mean rows into a
// 32 KB LDS bf16 A-tile (16B-granule XOR swizzle), then MFMA chunk r+1 into the
// persistent accumulators. Chunk 0 (root) reads A straight from global xb.
// K = 1152 never round-trips HBM: the old 205 MB sums write + 205 MB read are gone.
__global__ __launch_bounds__(512, 4)   // 4 waves/EU -> 2 blocks/CU; VGPR budget 128
void rgcn_fused(const int* __restrict__ ends, const int* __restrict__ perm,
                const short* __restrict__ xb, const short* __restrict__ Bsw,
                const float* __restrict__ bias, float* __restrict__ out) {
    __shared__ short Ash[128 * 128];   // 32 KB bf16 A-tile, swizzled: chunk16 ^= (row&7)
    __shared__ int lends[1026];        // ends[B0*8-1 .. B0*8+1023] (segment boundaries)
    const int tid = threadIdx.x;
    const int wave = tid >> 6, lane = tid & 63;
    const int m16 = lane & 15, quad = lane >> 4;
    const int wm = wave >> 2, wn = wave & 3;     // wave tile: 64 rows x 32 cols
    const long B0 = (long)blockIdx.x * 128;

    // stage segment boundaries; clamp: key<0 -> 0, key>=N_KEYS -> N_EDGES (empty segs)
    for (int i = tid; i < 1025; i += 512) {
        long idx = B0 * 8 - 1 + i;
        int v;
        if (idx < 0) v = 0;
        else if (idx >= N_KEYS) v = N_EDGES;
        else v = ends[idx];
        lends[i] = v;
    }

    float bcol[2];
#pragma unroll
    for (int ct = 0; ct < 2; ++ct) bcol[ct] = bias[wn * 32 + ct * 16 + m16];

    frag_cd acc[4][2];
#pragma unroll
    for (int mt = 0; mt < 4; ++mt)
#pragma unroll
        for (int ct = 0; ct < 2; ++ct) acc[mt][ct] = (frag_cd){0.f, 0.f, 0.f, 0.f};

    __syncthreads();

    // ---- chunk 0: root weight, A-fragments direct from global xb ----
#pragma unroll
    for (int ks = 0; ks < 4; ++ks) {
        frag_ab af[4];
#pragma unroll
        for (int mt = 0; mt < 4; ++mt)
            af[mt] = *(const frag_ab*)(xb + (B0 + wm * 64 + mt * 16 + m16) * CH + ks * 32 + quad * 8);
#pragma unroll
        for (int ct = 0; ct < 2; ++ct) {
            frag_ab bf = *(const frag_ab*)(Bsw + (size_t)((((ks * 4 + quad) * 8) + wn * 2 + ct) * 16 + m16) * 8);
#pragma unroll
            for (int mt = 0; mt < 4; ++mt)
                acc[mt][ct] = __builtin_amdgcn_mfma_f32_16x16x32_bf16(af[mt], bf, acc[mt][ct], 0, 0, 0);
        }
    }

    const uint32_t ch16 = (uint32_t)m16 << 4;    // this lane's 16B channel slice
    const char* xbp = (const char*)xb;

    for (int r = 0; r < N_REL; ++r) {
        // ---- aggregate relation r: each 16-lane group owns one dst row ----
#pragma unroll 1
        for (int b = 0; b < 4; ++b) {
            const int lrow = (wave << 4) + (b << 2) + quad;   // 0..127, unique per (wave,b,quad)
            const int keyL = lrow * 8 + r;
            const int s = lends[keyL];
            const int e = lends[keyL + 1];
            float a0 = 0.f, a1 = 0.f, a2 = 0.f, a3 = 0.f, a4 = 0.f, a5 = 0.f, a6 = 0.f, a7 = 0.f;
            int p = perm[(s < e) ? s : 0];                    // prefetch first src
            for (int k = s; k < e; ++k) {
                const uint4 u = *(const uint4*)(xbp + (((uint32_t)p << 8) | ch16));
                const int kn = k + 1;
                p = perm[(kn < e) ? kn : 0];                  // prefetch next (hides under gather)
                a0 += bf_lo(u.x); a1 += bf_hi(u.x);
                a2 += bf_lo(u.y); a3 += bf_hi(u.y);
                a4 += bf_lo(u.z); a5 += bf_hi(u.z);
                a6 += bf_lo(u.w); a7 += bf_hi(u.w);
            }
            const int c = e - s;
            const float sc = (c > 1) ? (1.0f / (float)c) : 1.0f;
            uint4 w;
            w.x = pack2bf(a0 * sc, a1 * sc);
            w.y = pack2bf(a2 * sc, a3 * sc);
            w.z = pack2bf(a4 * sc, a5 * sc);
            w.w = pack2bf(a6 * sc, a7 * sc);
            // swizzled A-tile write (empty segment -> zeros, every row gets written)
            *(uint4*)((char*)Ash + lrow * 256 + ((m16 ^ (lrow & 7)) << 4)) = w;
        }
        __syncthreads();
        // ---- MFMA chunk r+1: A from LDS (swizzled ds_read_b128), B from L2-hot Bsw ----
        const short* Bc = Bsw + (size_t)(r + 1) * 2048 * 8;
#pragma unroll
        for (int ks = 0; ks < 4; ++ks) {
            frag_ab af[4];
#pragma unroll
            for (int mt = 0; mt < 4; ++mt) {
                const int lr = wm * 64 + mt * 16 + m16;
                af[mt] = *(const frag_ab*)((const char*)Ash + lr * 256 + (((ks * 4 + quad) ^ (lr & 7)) << 4));
            }
#pragma unroll
            for (int ct = 0; ct < 2; ++ct) {
                frag_ab bf = *(const frag_ab*)(Bc + (size_t)((((ks * 4 + quad) * 8) + wn * 2 + ct) * 16 + m16) * 8);
#pragma unroll
                for (int mt = 0; mt < 4; ++mt)
                    acc[mt][ct] = __builtin_amdgcn_mfma_f32_16x16x32_bf16(af[mt], bf, acc[mt][ct], 0, 0, 0);
            }
        }
        __syncthreads();
    }

    // ---- epilogue ----
#pragma unroll
    for (int mt = 0; mt < 4; ++mt) {
#pragma unroll
        for (int ct = 0; ct < 2; ++ct) {
            const long row0 = B0 + wm * 64 + mt * 16 + quad * 4;
            const int col = wn * 32 + ct * 16 + m16;
#pragma unroll
            for (int rg = 0; rg < 4; ++rg) {
                const long rr = row0 + rg;
                if (rr < N_NODES) out[rr * CH + col] = acc[mt][ct][rg] + bcol[ct];
            }
        }
    }
}

// ======================= fallback tiers (round-1 code) =======================

__global__ void count_rd_kernel(const int* __restrict__ ei, const int* __restrict__ et,
                                int* __restrict__ cnt) {
    int e = blockIdx.x * 256 + threadIdx.x;
    if (e < N_EDGES) {
        int dst = ei[N_EDGES + e];
        int r = et[e];
        atomicAdd(&cnt[r * N_NODES + dst], 1);
    }
}

__global__ void scatter_kernel(const int* __restrict__ ei, const int* __restrict__ et,
                               const float* __restrict__ x, float* __restrict__ sums,
                               int rel) {
    int gid = (blockIdx.x * 256 + threadIdx.x) >> 5;
    int lane = threadIdx.x & 31;
    int ngroups = gridDim.x * 8;
    for (int e = gid; e < N_EDGES; e += ngroups) {
        if (et[e] != rel) continue;
        int src = ei[e];
        int dst = ei[N_EDGES + e];
        float4 v = ((const float4*)(x + (size_t)src * CH))[lane];
        float* s = sums + (size_t)dst * CH + (size_t)lane * 4;
        atomicAdd(s + 0, v.x);
        atomicAdd(s + 1, v.y);
        atomicAdd(s + 2, v.z);
        atomicAdd(s + 3, v.w);
    }
}

__global__ __launch_bounds__(256, 2)
void gemm_kernel(const float* __restrict__ A, const float* __restrict__ B,
                 const float* __restrict__ bias, const int* __restrict__ cnt,
                 float* __restrict__ out, int accumulate) {
    const int wave = threadIdx.x >> 6;
    const int lane = threadIdx.x & 63;
    const int m16 = lane & 15;
    const int quad = lane >> 4;

    frag_ab bfrag[4][8];
#pragma unroll
    for (int ks = 0; ks < 4; ++ks) {
        const int kb = ks * 32 + quad * 8;
#pragma unroll
        for (int ct = 0; ct < 8; ++ct) {
            const int col = ct * 16 + m16;
            frag_ab f;
#pragma unroll
            for (int j = 0; j < 8; ++j)
                f[j] = f2bs(B[(size_t)(kb + j) * CH + col]);
            bfrag[ks][ct] = f;
        }
    }

    const int nstrips = (N_NODES + 63) / 64;
    for (int strip = blockIdx.x; strip < nstrips; strip += gridDim.x) {
        const int row = strip * 64 + wave * 16 + m16;
        const bool valid = row < N_NODES;
        float scale = 1.0f;
        if (cnt != nullptr && valid) {
            int c = cnt[row];
            if (c > 1) scale = 1.0f / (float)c;
        }
        const float4* arow = (const float4*)(A + (size_t)(valid ? row : 0) * CH);
        frag_cd acc[8];
#pragma unroll
        for (int ct = 0; ct < 8; ++ct) acc[ct] = (frag_cd){0.f, 0.f, 0.f, 0.f};
#pragma unroll
        for (int ks = 0; ks < 4; ++ks) {
            float4 a0 = arow[ks * 8 + quad * 2];
            float4 a1 = arow[ks * 8 + quad * 2 + 1];
            frag_ab af;
            af[0] = f2bs(a0.x * scale); af[1] = f2bs(a0.y * scale);
            af[2] = f2bs(a0.z * scale); af[3] = f2bs(a0.w * scale);
            af[4] = f2bs(a1.x * scale); af[5] = f2bs(a1.y * scale);
            af[6] = f2bs(a1.z * scale); af[7] = f2bs(a1.w * scale);
#pragma unroll
            for (int ct = 0; ct < 8; ++ct)
                acc[ct] = __builtin_amdgcn_mfma_f32_16x16x32_bf16(af, bfrag[ks][ct], acc[ct], 0, 0, 0);
        }
        const int obase = strip * 64 + wave * 16 + quad * 4;
#pragma unroll
        for (int ct = 0; ct < 8; ++ct) {
            const int col = ct * 16 + m16;
#pragma unroll
            for (int rg = 0; rg < 4; ++rg) {
                const int r = obase + rg;
                if (r < N_NODES) {
                    const size_t idx = (size_t)r * CH + col;
                    if (accumulate) out[idx] += acc[ct][rg];
                    else out[idx] = acc[ct][rg] + bias[col];
                }
            }
        }
    }
}

__global__ void edge_transform_kernel(const int* __restrict__ ei, const int* __restrict__ et,
                                      const float* __restrict__ x, const float* __restrict__ W,
                                      const int* __restrict__ cnt, float* __restrict__ out) {
    __shared__ float xs[CH];
    const int tid = threadIdx.x;
    for (int e = blockIdx.x; e < N_EDGES; e += gridDim.x) {
        const int src = ei[e];
        const int dst = ei[N_EDGES + e];
        const int r = et[e];
        __syncthreads();
        xs[tid] = x[(size_t)src * CH + tid];
        __syncthreads();
        const int c = cnt[r * N_NODES + dst];
        const float scale = (c > 1) ? (1.0f / (float)c) : 1.0f;
        const float* Wr = W + (size_t)r * CH * CH;
        float acc = 0.f;
#pragma unroll 8
        for (int k = 0; k < CH; ++k) acc += xs[k] * Wr[(size_t)k * CH + tid];
        atomicAdd(&out[(size_t)dst * CH + tid], acc * scale);
    }
}

// ======================= launch =======================

static inline size_t al512(size_t x) { return (x + 511) & ~(size_t)511; }

extern "C" void kernel_launch(void* const* d_in, const int* in_sizes, int n_in,
                              void* d_out, int out_size, void* d_ws, size_t ws_size,
                              hipStream_t stream) {
    const float* x    = (const float*)d_in[0];
    const int*   ei   = (const int*)d_in[1];   // [2, E]: row0=src, row1=dst
    const int*   et   = (const int*)d_in[2];   // [E]
    const float* W    = (const float*)d_in[3]; // [R,128,128]
    const float* root = (const float*)d_in[4]; // [128,128]
    const float* bias = (const float*)d_in[5]; // [128]
    float* out = (float*)d_out;

    // ---- tier-1 workspace layout (key = dst*8+rel); no sums array anymore ----
    size_t o = 0;
    const size_t o_cnt  = o; o += al512((size_t)N_KEYS * 4);         // offs/ends in place
    const size_t o_bsum = o; o += al512((size_t)SCAN_BLOCKS_K * 4);
    const size_t o_perm = o; o += al512((size_t)N_EDGES * 4);
    const size_t o_bsw  = o; o += al512((size_t)9 * 2048 * 16);
    const size_t o_xb   = o; o += al512((size_t)N_PAD * CH * 2);
    const size_t need_t1 = o;

    const size_t cnt_bytes = (size_t)N_REL * N_NODES * sizeof(int);
    const size_t cnt_rsv   = al512(cnt_bytes);
    const size_t sums51    = (size_t)N_NODES * CH * sizeof(float);

    char* ws = (char*)d_ws;
    if (ws_size >= need_t1) {
        int*   cnt  = (int*)(ws + o_cnt);
        int*   bsum = (int*)(ws + o_bsum);
        int*   perm = (int*)(ws + o_perm);
        short* Bsw  = (short*)(ws + o_bsw);
        short* xb   = (short*)(ws + o_xb);

        hipMemsetAsync(cnt, 0, (size_t)N_KEYS * 4, stream);
        count_key_kernel<<<(N_EDGES + 255) / 256, 256, 0, stream>>>(ei, et, cnt);
        scan1_kernel<<<SCAN_BLOCKS_K, 256, 0, stream>>>(cnt, bsum, N_KEYS);
        scan2_kernel<<<1, 1024, 0, stream>>>(bsum, SCAN_BLOCKS_K);
        scan3_kernel<<<SCAN_BLOCKS_K, 256, 0, stream>>>(cnt, bsum, N_KEYS);
        permute_key_kernel<<<(N_EDGES + 255) / 256, 256, 0, stream>>>(ei, et, cnt, perm);
        xconv_kernel<<<(N_NODES * CH / 8 + 255) / 256, 256, 0, stream>>>(x, xb);
        bconv_kernel<<<(9 * 2048 + 255) / 256, 256, 0, stream>>>(root, W, Bsw);
        rgcn_fused<<<N_PAD / 128, 512, 0, stream>>>(cnt, perm, xb, Bsw, bias, out);
    } else if (ws_size >= cnt_rsv + sums51) {
        int*   cnt  = (int*)d_ws;
        float* sums = (float*)((char*)d_ws + cnt_rsv);
        hipMemsetAsync(cnt, 0, cnt_bytes, stream);
        count_rd_kernel<<<(N_EDGES + 255) / 256, 256, 0, stream>>>(ei, et, cnt);
        gemm_kernel<<<512, 256, 0, stream>>>(x, root, bias, nullptr, out, 0);
        for (int r = 0; r < N_REL; ++r) {
            hipMemsetAsync(sums, 0, sums51, stream);
            scatter_kernel<<<6400, 256, 0, stream>>>(ei, et, x, sums, r);
            gemm_kernel<<<512, 256, 0, stream>>>(sums, W + (size_t)r * CH * CH,
                                                 nullptr, cnt + (size_t)r * N_NODES, out, 1);
        }
    } else {
        int* cnt = (int*)d_ws;
        hipMemsetAsync(cnt, 0, cnt_bytes, stream);
        count_rd_kernel<<<(N_EDGES + 255) / 256, 256, 0, stream>>>(ei, et, cnt);
        gemm_kernel<<<512, 256, 0, stream>>>(x, root, bias, nullptr, out, 0);
        edge_transform_kernel<<<65536, CH, 0, stream>>>(ei, et, x, W, cnt, out);
    }
}

// Round 2
// 441.846 us; speedup vs baseline: 1.2434x; 1.1849x over previous
//
#include <hip/hip_runtime.h>
#include <hip/hip_bf16.h>
#include <stdint.h>

#define N_NODES 100000
#define N_EDGES 1600000
#define CH 128
#define N_REL 8
#define N_PAD 100096            // N_NODES rounded up to multiple of 128 (GEMM strip pad)
#define N_KEYS (N_NODES * N_REL)

#define SCAN_BLOCKS_K 782       // ceil(N_KEYS / 1024)
#define SCAN_BLOCKS_D 98        // ceil(N_NODES / 1024)

using frag_ab = __attribute__((ext_vector_type(8))) short;  // 8 bf16
using frag_cd = __attribute__((ext_vector_type(4))) float;  // 4 fp32

__device__ __forceinline__ short f2bs(float f) {
    union { __hip_bfloat16 h; short s; } u;
    u.h = __float2bfloat16(f);
    return u.s;
}

__device__ __forceinline__ uint32_t pack2bf(float a, float b) {
    union { __hip_bfloat16 h; unsigned short s; } ua, ub;
    ua.h = __float2bfloat16(a); ub.h = __float2bfloat16(b);
    return (uint32_t)ua.s | ((uint32_t)ub.s << 16);
}

__device__ __forceinline__ float bf_lo(uint32_t u) { return __uint_as_float(u << 16); }
__device__ __forceinline__ float bf_hi(uint32_t u) { return __uint_as_float(u & 0xffff0000u); }

// ======================= TIER 1: CSR keyed by (dst*8 + rel) =======================

__global__ void count_key_kernel(const int* __restrict__ ei, const int* __restrict__ et,
                                 int* __restrict__ cnt) {
    int e = blockIdx.x * 256 + threadIdx.x;
    if (e < N_EDGES) {
        int dst = ei[N_EDGES + e];
        int r = et[e];
        atomicAdd(&cnt[dst * N_REL + r], 1);
    }
}

// --- generic two-level scan, 1024 elements per block (256 thr x int4) ---
__global__ void scan1_kernel(const int* __restrict__ cnt, int* __restrict__ bsum, int n) {
    __shared__ int sh[256];
    const int t = threadIdx.x;
    const int base = blockIdx.x * 1024 + t * 4;
    int s = 0;
    if (base + 3 < n) {
        int4 v = *(const int4*)(cnt + base);
        s = v.x + v.y + v.z + v.w;
    } else {
        for (int i = 0; i < 4; ++i) if (base + i < n) s += cnt[base + i];
    }
    sh[t] = s;
    __syncthreads();
    for (int st = 128; st > 0; st >>= 1) {
        if (t < st) sh[t] += sh[t + st];
        __syncthreads();
    }
    if (t == 0) bsum[blockIdx.x] = sh[0];
}

__global__ void scan2_kernel(int* __restrict__ bsum, int nb) {
    __shared__ int sh[1024];
    const int t = threadIdx.x;
    int v = (t < nb) ? bsum[t] : 0;
    sh[t] = v;
    __syncthreads();
    for (int s = 1; s < 1024; s <<= 1) {
        int u = (t >= s) ? sh[t - s] : 0;
        __syncthreads();
        sh[t] += u;
        __syncthreads();
    }
    if (t < nb) bsum[t] = sh[t] - v;   // exclusive
}

// in-place: cnt[i] <- exclusive_prefix_sum(cnt)[i]
__global__ void scan3_kernel(int* __restrict__ cnt, const int* __restrict__ bsum, int n) {
    __shared__ int sh[256];
    const int t = threadIdx.x;
    const int base = blockIdx.x * 1024 + t * 4;
    int4 v = make_int4(0, 0, 0, 0);
    if (base + 3 < n) {
        v = *(const int4*)(cnt + base);
    } else {
        if (base + 0 < n) v.x = cnt[base + 0];
        if (base + 1 < n) v.y = cnt[base + 1];
        if (base + 2 < n) v.z = cnt[base + 2];
        if (base + 3 < n) v.w = cnt[base + 3];
    }
    const int s = v.x + v.y + v.z + v.w;
    sh[t] = s;
    __syncthreads();
    for (int st = 1; st < 256; st <<= 1) {      // Hillis-Steele inclusive
        int u = (t >= st) ? sh[t - st] : 0;
        __syncthreads();
        sh[t] += u;
        __syncthreads();
    }
    int run = bsum[blockIdx.x] + sh[t] - s;     // exclusive prefix for this thread
    const int o0 = run, o1 = o0 + v.x, o2 = o1 + v.y, o3 = o2 + v.z;
    if (base + 3 < n) {
        *(int4*)(cnt + base) = make_int4(o0, o1, o2, o3);
    } else {
        if (base + 0 < n) cnt[base + 0] = o0;
        if (base + 1 < n) cnt[base + 1] = o1;
        if (base + 2 < n) cnt[base + 2] = o2;
        if (base + 3 < n) cnt[base + 3] = o3;
    }
}

// scatter src into (dst,rel)-sorted slots; offs[] doubles as cursor and ends as segment-END
__global__ void permute_key_kernel(const int* __restrict__ ei, const int* __restrict__ et,
                                   int* __restrict__ offs, int* __restrict__ perm) {
    int e = blockIdx.x * 256 + threadIdx.x;
    if (e < N_EDGES) {
        int dst = ei[N_EDGES + e];
        int src = ei[e];
        int r = et[e];
        int pos = atomicAdd(&offs[dst * N_REL + r], 1);
        perm[pos] = src;
    }
}

// ======================= shared helpers =======================

// x fp32 -> bf16 (flat copy of N*128 elements)
__global__ void xconv_kernel(const float* __restrict__ x, short* __restrict__ xb) {
    int g = blockIdx.x * 256 + threadIdx.x;       // one per 8 elements
    if (g >= N_NODES * CH / 8) return;
    const float4* xp = (const float4*)x;
    float4 a = xp[(size_t)g * 2], b = xp[(size_t)g * 2 + 1];
    frag_ab f;
    f[0] = f2bs(a.x); f[1] = f2bs(a.y); f[2] = f2bs(a.z); f[3] = f2bs(a.w);
    f[4] = f2bs(b.x); f[5] = f2bs(b.y); f[6] = f2bs(b.z); f[7] = f2bs(b.w);
    *(frag_ab*)(xb + (size_t)g * 8) = f;
}

// build swizzled bf16 B: Bsw[chunk][entry][8], entry = ((ks*4+quad)*8+ct)*16+m16
__global__ void bconv_kernel(const float* __restrict__ root, const float* __restrict__ W,
                             short* __restrict__ Bsw) {
    int g = blockIdx.x * 256 + threadIdx.x;
    if (g >= 9 * 2048) return;
    int chunk = g >> 11, entry = g & 2047;
    int m16 = entry & 15, ct = (entry >> 4) & 7, quad = (entry >> 7) & 3, ks = entry >> 9;
    const float* src = (chunk == 0) ? root : W + (size_t)(chunk - 1) * CH * CH;
    int col = ct * 16 + m16, kb = ks * 32 + quad * 8;
    frag_ab f;
#pragma unroll
    for (int j = 0; j < 8; ++j) f[j] = f2bs(src[(size_t)(kb + j) * CH + col]);
    *(frag_ab*)(Bsw + (size_t)g * 8) = f;
}

// ======================= FUSED aggregate + GEMM =======================
// One block = 128 output rows. Per relation r: aggregate the 128 mean rows into a
// 32 KB LDS bf16 A-tile (16B-granule XOR swizzle), then MFMA chunk r+1 into the
// persistent accumulators. Chunk 0 (root) reads A straight from global xb.
//
// R2 aggregation rework for memory-level parallelism (R1 was latency-bound:
// HBM 14%, VALU 19%, MfmaUtil 5%): 8-lane groups (32B/lane) -> 8 concurrent
// segment chains per wave (2 row-steps), edge-unroll x2 with clamped tail
// -> 4 outstanding 32B gathers per chain, perm prefetched across rounds.
// Median segment length is 2 (E/(N*R)), so most segments finish in ONE
// latency round.
#define ACC16(U0, U1)                                           \
    do {                                                        \
        a0 += bf_lo((U0).x);  a1 += bf_hi((U0).x);              \
        a2 += bf_lo((U0).y);  a3 += bf_hi((U0).y);              \
        a4 += bf_lo((U0).z);  a5 += bf_hi((U0).z);              \
        a6 += bf_lo((U0).w);  a7 += bf_hi((U0).w);              \
        a8 += bf_lo((U1).x);  a9 += bf_hi((U1).x);              \
        a10 += bf_lo((U1).y); a11 += bf_hi((U1).y);             \
        a12 += bf_lo((U1).z); a13 += bf_hi((U1).z);             \
        a14 += bf_lo((U1).w); a15 += bf_hi((U1).w);             \
    } while (0)

__global__ __launch_bounds__(512, 4)
void rgcn_fused(const int* __restrict__ ends, const int* __restrict__ perm,
                const short* __restrict__ xb, const short* __restrict__ Bsw,
                const float* __restrict__ bias, float* __restrict__ out) {
    __shared__ short Ash[128 * 128];   // 32 KB bf16 A-tile, swizzled: chunk16 ^= (row&7)
    __shared__ int lends[1026];        // ends[B0*8-1 .. B0*8+1023] (segment boundaries)
    const int tid = threadIdx.x;
    const int wave = tid >> 6, lane = tid & 63;
    const int m16 = lane & 15, quad = lane >> 4;
    const int grp = lane >> 3, sub = lane & 7;   // 8-lane gather groups
    const int wm = wave >> 2, wn = wave & 3;     // wave tile: 64 rows x 32 cols
    const long B0 = (long)blockIdx.x * 128;

    // stage segment boundaries; clamp: key<0 -> 0, key>=N_KEYS -> N_EDGES (empty segs)
    for (int i = tid; i < 1025; i += 512) {
        long idx = B0 * 8 - 1 + i;
        int v;
        if (idx < 0) v = 0;
        else if (idx >= N_KEYS) v = N_EDGES;
        else v = ends[idx];
        lends[i] = v;
    }

    float bcol[2];
#pragma unroll
    for (int ct = 0; ct < 2; ++ct) bcol[ct] = bias[wn * 32 + ct * 16 + m16];

    frag_cd acc[4][2];
#pragma unroll
    for (int mt = 0; mt < 4; ++mt)
#pragma unroll
        for (int ct = 0; ct < 2; ++ct) acc[mt][ct] = (frag_cd){0.f, 0.f, 0.f, 0.f};

    __syncthreads();

    // ---- chunk 0: root weight, A-fragments direct from global xb ----
#pragma unroll
    for (int ks = 0; ks < 4; ++ks) {
        frag_ab af[4];
#pragma unroll
        for (int mt = 0; mt < 4; ++mt)
            af[mt] = *(const frag_ab*)(xb + (B0 + wm * 64 + mt * 16 + m16) * CH + ks * 32 + quad * 8);
#pragma unroll
        for (int ct = 0; ct < 2; ++ct) {
            frag_ab bf = *(const frag_ab*)(Bsw + (size_t)((((ks * 4 + quad) * 8) + wn * 2 + ct) * 16 + m16) * 8);
#pragma unroll
            for (int mt = 0; mt < 4; ++mt)
                acc[mt][ct] = __builtin_amdgcn_mfma_f32_16x16x32_bf16(af[mt], bf, acc[mt][ct], 0, 0, 0);
        }
    }

    const uint32_t ch32 = (uint32_t)sub << 5;    // this lane's 32B channel slice
    const char* xbp = (const char*)xb;

    for (int r = 0; r < N_REL; ++r) {
        // ---- aggregate relation r: each 8-lane group owns one dst row ----
#pragma unroll
        for (int step = 0; step < 2; ++step) {
            const int lrow = (wave << 4) + (step << 3) + grp;   // 0..127 unique per (wave,step,grp)
            const int keyL = lrow * 8 + r;
            const int s = lends[keyL];
            const int e = lends[keyL + 1];
            float a0 = 0.f, a1 = 0.f, a2 = 0.f, a3 = 0.f;
            float a4 = 0.f, a5 = 0.f, a6 = 0.f, a7 = 0.f;
            float a8 = 0.f, a9 = 0.f, a10 = 0.f, a11 = 0.f;
            float a12 = 0.f, a13 = 0.f, a14 = 0.f, a15 = 0.f;
            // prefetch indices for the first edge pair (clamped; harmless dup loads)
            int p0 = perm[(s < e) ? s : 0];
            int p1 = perm[(s + 1 < e) ? s + 1 : ((s < e) ? s : 0)];
            for (int k = s; k < e; k += 2) {
                const char* b0 = xbp + (((size_t)(uint32_t)p0 << 8) | ch32);
                const char* b1 = xbp + (((size_t)(uint32_t)p1 << 8) | ch32);
                const uint4 u0 = *(const uint4*)(b0);
                const uint4 u1 = *(const uint4*)(b0 + 16);
                const uint4 u2 = *(const uint4*)(b1);
                const uint4 u3 = *(const uint4*)(b1 + 16);
                const int kn = k + 2;
                p0 = perm[(kn < e) ? kn : 0];                  // prefetch next pair
                p1 = perm[(kn + 1 < e) ? kn + 1 : 0];
                ACC16(u0, u1);
                if (k + 1 < e) ACC16(u2, u3);
            }
            const int c = e - s;
            const float sc = (c > 1) ? (1.0f / (float)c) : 1.0f;
            uint4 w0, w1;
            w0.x = pack2bf(a0 * sc, a1 * sc);
            w0.y = pack2bf(a2 * sc, a3 * sc);
            w0.z = pack2bf(a4 * sc, a5 * sc);
            w0.w = pack2bf(a6 * sc, a7 * sc);
            w1.x = pack2bf(a8 * sc, a9 * sc);
            w1.y = pack2bf(a10 * sc, a11 * sc);
            w1.z = pack2bf(a12 * sc, a13 * sc);
            w1.w = pack2bf(a14 * sc, a15 * sc);
            // swizzled A-tile write (empty segment -> zeros, every row gets written)
            char* drow = (char*)Ash + lrow * 256;
            const int swz = lrow & 7;
            *(uint4*)(drow + ((((sub << 1)    ) ^ swz) << 4)) = w0;
            *(uint4*)(drow + ((((sub << 1) | 1) ^ swz) << 4)) = w1;
        }
        __syncthreads();
        // ---- MFMA chunk r+1: A from LDS (swizzled ds_read_b128), B from L2-hot Bsw ----
        const short* Bc = Bsw + (size_t)(r + 1) * 2048 * 8;
#pragma unroll
        for (int ks = 0; ks < 4; ++ks) {
            frag_ab af[4];
#pragma unroll
            for (int mt = 0; mt < 4; ++mt) {
                const int lr = wm * 64 + mt * 16 + m16;
                af[mt] = *(const frag_ab*)((const char*)Ash + lr * 256 + (((ks * 4 + quad) ^ (lr & 7)) << 4));
            }
#pragma unroll
            for (int ct = 0; ct < 2; ++ct) {
                frag_ab bf = *(const frag_ab*)(Bc + (size_t)((((ks * 4 + quad) * 8) + wn * 2 + ct) * 16 + m16) * 8);
#pragma unroll
                for (int mt = 0; mt < 4; ++mt)
                    acc[mt][ct] = __builtin_amdgcn_mfma_f32_16x16x32_bf16(af[mt], bf, acc[mt][ct], 0, 0, 0);
            }
        }
        __syncthreads();
    }

    // ---- epilogue ----
#pragma unroll
    for (int mt = 0; mt < 4; ++mt) {
#pragma unroll
        for (int ct = 0; ct < 2; ++ct) {
            const long row0 = B0 + wm * 64 + mt * 16 + quad * 4;
            const int col = wn * 32 + ct * 16 + m16;
#pragma unroll
            for (int rg = 0; rg < 4; ++rg) {
                const long rr = row0 + rg;
                if (rr < N_NODES) out[rr * CH + col] = acc[mt][ct][rg] + bcol[ct];
            }
        }
    }
}

// ======================= fallback tiers (round-1 code) =======================

__global__ void count_rd_kernel(const int* __restrict__ ei, const int* __restrict__ et,
                                int* __restrict__ cnt) {
    int e = blockIdx.x * 256 + threadIdx.x;
    if (e < N_EDGES) {
        int dst = ei[N_EDGES + e];
        int r = et[e];
        atomicAdd(&cnt[r * N_NODES + dst], 1);
    }
}

__global__ void scatter_kernel(const int* __restrict__ ei, const int* __restrict__ et,
                               const float* __restrict__ x, float* __restrict__ sums,
                               int rel) {
    int gid = (blockIdx.x * 256 + threadIdx.x) >> 5;
    int lane = threadIdx.x & 31;
    int ngroups = gridDim.x * 8;
    for (int e = gid; e < N_EDGES; e += ngroups) {
        if (et[e] != rel) continue;
        int src = ei[e];
        int dst = ei[N_EDGES + e];
        float4 v = ((const float4*)(x + (size_t)src * CH))[lane];
        float* s = sums + (size_t)dst * CH + (size_t)lane * 4;
        atomicAdd(s + 0, v.x);
        atomicAdd(s + 1, v.y);
        atomicAdd(s + 2, v.z);
        atomicAdd(s + 3, v.w);
    }
}

__global__ __launch_bounds__(256, 2)
void gemm_kernel(const float* __restrict__ A, const float* __restrict__ B,
                 const float* __restrict__ bias, const int* __restrict__ cnt,
                 float* __restrict__ out, int accumulate) {
    const int wave = threadIdx.x >> 6;
    const int lane = threadIdx.x & 63;
    const int m16 = lane & 15;
    const int quad = lane >> 4;

    frag_ab bfrag[4][8];
#pragma unroll
    for (int ks = 0; ks < 4; ++ks) {
        const int kb = ks * 32 + quad * 8;
#pragma unroll
        for (int ct = 0; ct < 8; ++ct) {
            const int col = ct * 16 + m16;
            frag_ab f;
#pragma unroll
            for (int j = 0; j < 8; ++j)
                f[j] = f2bs(B[(size_t)(kb + j) * CH + col]);
            bfrag[ks][ct] = f;
        }
    }

    const int nstrips = (N_NODES + 63) / 64;
    for (int strip = blockIdx.x; strip < nstrips; strip += gridDim.x) {
        const int row = strip * 64 + wave * 16 + m16;
        const bool valid = row < N_NODES;
        float scale = 1.0f;
        if (cnt != nullptr && valid) {
            int c = cnt[row];
            if (c > 1) scale = 1.0f / (float)c;
        }
        const float4* arow = (const float4*)(A + (size_t)(valid ? row : 0) * CH);
        frag_cd acc[8];
#pragma unroll
        for (int ct = 0; ct < 8; ++ct) acc[ct] = (frag_cd){0.f, 0.f, 0.f, 0.f};
#pragma unroll
        for (int ks = 0; ks < 4; ++ks) {
            float4 a0 = arow[ks * 8 + quad * 2];
            float4 a1 = arow[ks * 8 + quad * 2 + 1];
            frag_ab af;
            af[0] = f2bs(a0.x * scale); af[1] = f2bs(a0.y * scale);
            af[2] = f2bs(a0.z * scale); af[3] = f2bs(a0.w * scale);
            af[4] = f2bs(a1.x * scale); af[5] = f2bs(a1.y * scale);
            af[6] = f2bs(a1.z * scale); af[7] = f2bs(a1.w * scale);
#pragma unroll
            for (int ct = 0; ct < 8; ++ct)
                acc[ct] = __builtin_amdgcn_mfma_f32_16x16x32_bf16(af, bfrag[ks][ct], acc[ct], 0, 0, 0);
        }
        const int obase = strip * 64 + wave * 16 + quad * 4;
#pragma unroll
        for (int ct = 0; ct < 8; ++ct) {
            const int col = ct * 16 + m16;
#pragma unroll
            for (int rg = 0; rg < 4; ++rg) {
                const int r = obase + rg;
                if (r < N_NODES) {
                    const size_t idx = (size_t)r * CH + col;
                    if (accumulate) out[idx] += acc[ct][rg];
                    else out[idx] = acc[ct][rg] + bias[col];
                }
            }
        }
    }
}

__global__ void edge_transform_kernel(const int* __restrict__ ei, const int* __restrict__ et,
                                      const float* __restrict__ x, const float* __restrict__ W,
                                      const int* __restrict__ cnt, float* __restrict__ out) {
    __shared__ float xs[CH];
    const int tid = threadIdx.x;
    for (int e = blockIdx.x; e < N_EDGES; e += gridDim.x) {
        const int src = ei[e];
        const int dst = ei[N_EDGES + e];
        const int r = et[e];
        __syncthreads();
        xs[tid] = x[(size_t)src * CH + tid];
        __syncthreads();
        const int c = cnt[r * N_NODES + dst];
        const float scale = (c > 1) ? (1.0f / (float)c) : 1.0f;
        const float* Wr = W + (size_t)r * CH * CH;
        float acc = 0.f;
#pragma unroll 8
        for (int k = 0; k < CH; ++k) acc += xs[k] * Wr[(size_t)k * CH + tid];
        atomicAdd(&out[(size_t)dst * CH + tid], acc * scale);
    }
}

// ======================= launch =======================

static inline size_t al512(size_t x) { return (x + 511) & ~(size_t)511; }

extern "C" void kernel_launch(void* const* d_in, const int* in_sizes, int n_in,
                              void* d_out, int out_size, void* d_ws, size_t ws_size,
                              hipStream_t stream) {
    const float* x    = (const float*)d_in[0];
    const int*   ei   = (const int*)d_in[1];   // [2, E]: row0=src, row1=dst
    const int*   et   = (const int*)d_in[2];   // [E]
    const float* W    = (const float*)d_in[3]; // [R,128,128]
    const float* root = (const float*)d_in[4]; // [128,128]
    const float* bias = (const float*)d_in[5]; // [128]
    float* out = (float*)d_out;

    // ---- tier-1 workspace layout (key = dst*8+rel); no sums array anymore ----
    size_t o = 0;
    const size_t o_cnt  = o; o += al512((size_t)N_KEYS * 4);         // offs/ends in place
    const size_t o_bsum = o; o += al512((size_t)SCAN_BLOCKS_K * 4);
    const size_t o_perm = o; o += al512((size_t)N_EDGES * 4);
    const size_t o_bsw  = o; o += al512((size_t)9 * 2048 * 16);
    const size_t o_xb   = o; o += al512((size_t)N_PAD * CH * 2);
    const size_t need_t1 = o;

    const size_t cnt_bytes = (size_t)N_REL * N_NODES * sizeof(int);
    const size_t cnt_rsv   = al512(cnt_bytes);
    const size_t sums51    = (size_t)N_NODES * CH * sizeof(float);

    char* ws = (char*)d_ws;
    if (ws_size >= need_t1) {
        int*   cnt  = (int*)(ws + o_cnt);
        int*   bsum = (int*)(ws + o_bsum);
        int*   perm = (int*)(ws + o_perm);
        short* Bsw  = (short*)(ws + o_bsw);
        short* xb   = (short*)(ws + o_xb);

        hipMemsetAsync(cnt, 0, (size_t)N_KEYS * 4, stream);
        count_key_kernel<<<(N_EDGES + 255) / 256, 256, 0, stream>>>(ei, et, cnt);
        scan1_kernel<<<SCAN_BLOCKS_K, 256, 0, stream>>>(cnt, bsum, N_KEYS);
        scan2_kernel<<<1, 1024, 0, stream>>>(bsum, SCAN_BLOCKS_K);
        scan3_kernel<<<SCAN_BLOCKS_K, 256, 0, stream>>>(cnt, bsum, N_KEYS);
        permute_key_kernel<<<(N_EDGES + 255) / 256, 256, 0, stream>>>(ei, et, cnt, perm);
        xconv_kernel<<<(N_NODES * CH / 8 + 255) / 256, 256, 0, stream>>>(x, xb);
        bconv_kernel<<<(9 * 2048 + 255) / 256, 256, 0, stream>>>(root, W, Bsw);
        rgcn_fused<<<N_PAD / 128, 512, 0, stream>>>(cnt, perm, xb, Bsw, bias, out);
    } else if (ws_size >= cnt_rsv + sums51) {
        int*   cnt  = (int*)d_ws;
        float* sums = (float*)((char*)d_ws + cnt_rsv);
        hipMemsetAsync(cnt, 0, cnt_bytes, stream);
        count_rd_kernel<<<(N_EDGES + 255) / 256, 256, 0, stream>>>(ei, et, cnt);
        gemm_kernel<<<512, 256, 0, stream>>>(x, root, bias, nullptr, out, 0);
        for (int r = 0; r < N_REL; ++r) {
            hipMemsetAsync(sums, 0, sums51, stream);
            scatter_kernel<<<6400, 256, 0, stream>>>(ei, et, x, sums, r);
            gemm_kernel<<<512, 256, 0, stream>>>(sums, W + (size_t)r * CH * CH,
                                                 nullptr, cnt + (size_t)r * N_NODES, out, 1);
        }
    } else {
        int* cnt = (int*)d_ws;
        hipMemsetAsync(cnt, 0, cnt_bytes, stream);
        count_rd_kernel<<<(N_EDGES + 255) / 256, 256, 0, stream>>>(ei, et, cnt);
        gemm_kernel<<<512, 256, 0, stream>>>(x, root, bias, nullptr, out, 0);
        edge_transform_kernel<<<65536, CH, 0, stream>>>(ei, et, x, W, cnt, out);
    }
}